// Round 2
// baseline (121.406 us; speedup 1.0000x reference)
//
#include <hip/hip_runtime.h>

typedef unsigned short u16;
typedef __bf16 bf16;
typedef __bf16 bf16x8 __attribute__((ext_vector_type(8)));
typedef float f32x4 __attribute__((ext_vector_type(4)));

#define NTOK 32768
#define SCALE_F 0.17677669529663689f

__device__ __forceinline__ u16 f2bf(float f){
  unsigned u = __builtin_bit_cast(unsigned, f);
  u += 0x7fffu + ((u>>16)&1u);
  return (u16)(u>>16);
}
__device__ __forceinline__ float bf2f(u16 u){
  unsigned v = ((unsigned)u)<<16;
  return __builtin_bit_cast(float, v);
}

// ============ K1: k/v projection + exp(k) + ctx^T accumulation ============
// grid (64 chunks, 8 b), 256 thr. chunk = 512 tokens = 8 subtiles of 64.
// Wave w computes qkv rows 128+64w .. 128+64w+63 (w0,w1 -> k; w2,w3 -> v),
// then ctx^T[e][d] = sum_n v[e,n]*exp(k[d,n]) for head w (MFMA, f32 accum).
__global__ __launch_bounds__(256) void k1_ctx(const float* __restrict__ x,
    const float* __restrict__ wqkv, float* __restrict__ ctxP, float* __restrict__ s1P)
{
  const int b = blockIdx.y, chunk = blockIdx.x;
  const int t = threadIdx.x, w = t>>6, l = t&63, lr = l&15, lg = l>>4;
  __shared__ u16 xT[64*72];    // [n][c]
  __shared__ u16 ek[128*72];   // [k-ch][n]  exp(k) bf16
  __shared__ u16 vl[128*72];   // [v-ch][n]  v bf16

  // hoist A fragments (wqkv rows 128+64w..+63) into registers, f32 -> bf16
  bf16x8 afr[4][2];
  #pragma unroll
  for (int rt=0;rt<4;rt++)
    #pragma unroll
    for (int ks=0;ks<2;ks++){
      const float* src = wqkv + (128 + w*64 + rt*16 + lr)*64 + ks*32 + lg*8;
      #pragma unroll
      for (int j=0;j<8;j++) ((u16*)&afr[rt][ks])[j] = f2bf(src[j]);
    }

  f32x4 ctx[2][2];
  #pragma unroll
  for (int i=0;i<2;i++)
    #pragma unroll
    for (int j=0;j<2;j++) ctx[i][j] = f32x4{0.f,0.f,0.f,0.f};
  float s1a = 0.f;
  const float* xb = x + (long)b*64*NTOK;

  for (int s=0; s<8; s++) {
    const int n0 = chunk*512 + s*64;
    __syncthreads();
    { // stage x[64c][64n] -> xT[n][c] (f32 loads, bf16 stores)
      const int c = t>>2, j0 = (t&3)*16;
      #pragma unroll
      for (int i=0;i<4;i++){
        f32x4 v4 = *(const f32x4*)(xb + (long)c*NTOK + n0 + j0 + i*4);
        #pragma unroll
        for (int j=0;j<4;j++) xT[(j0+i*4+j)*72 + c] = f2bf(v4[j]);
      }
    }
    __syncthreads();
    f32x4 acc[4][4];
    #pragma unroll
    for (int rt=0;rt<4;rt++)
      #pragma unroll
      for (int ct=0;ct<4;ct++) acc[rt][ct] = f32x4{0.f,0.f,0.f,0.f};
    #pragma unroll
    for (int ks=0;ks<2;ks++){
      bf16x8 bfr[4];
      #pragma unroll
      for (int ct=0;ct<4;ct++)
        bfr[ct] = *(const bf16x8*)&xT[(ct*16+lr)*72 + ks*32 + lg*8];
      #pragma unroll
      for (int rt=0;rt<4;rt++){
        #pragma unroll
        for (int ct=0;ct<4;ct++)
          acc[rt][ct] = __builtin_amdgcn_mfma_f32_16x16x32_bf16(afr[rt][ks], bfr[ct], acc[rt][ct], 0,0,0);
      }
    }
    // C/D layout: col = l&15, row = (l>>4)*4 + ri
    if (w < 2) {
      #pragma unroll
      for (int rt=0;rt<4;rt++)
        #pragma unroll
        for (int ct=0;ct<4;ct++)
          #pragma unroll
          for (int ri=0;ri<4;ri++){
            const int ch = w*64 + rt*16 + lg*4 + ri;
            ek[ch*72 + ct*16 + lr] = f2bf(__expf(acc[rt][ct][ri]));
          }
    } else {
      #pragma unroll
      for (int rt=0;rt<4;rt++)
        #pragma unroll
        for (int ct=0;ct<4;ct++)
          #pragma unroll
          for (int ri=0;ri<4;ri++){
            const int ch = (w-2)*64 + rt*16 + lg*4 + ri;
            vl[ch*72 + ct*16 + lr] = f2bf(acc[rt][ct][ri]);
          }
    }
    __syncthreads();
    // ctx^T[e][d] += v[e][n]*ek[d][n], head = w. A=v rows(e), B=ek rows(d).
    #pragma unroll
    for (int ks=0;ks<2;ks++){
      bf16x8 bd[2];
      #pragma unroll
      for (int cd=0;cd<2;cd++)
        bd[cd] = *(const bf16x8*)&ek[(w*32 + cd*16 + lr)*72 + ks*32 + lg*8];
      #pragma unroll
      for (int re=0;re<2;re++){
        bf16x8 a = *(const bf16x8*)&vl[(w*32 + re*16 + lr)*72 + ks*32 + lg*8];
        #pragma unroll
        for (int cd=0;cd<2;cd++)
          ctx[re][cd] = __builtin_amdgcn_mfma_f32_16x16x32_bf16(a, bd[cd], ctx[re][cd], 0,0,0);
      }
    }
    { // S1 partial: thread covers (ch = t>>1, cols (t&1)*32..+31)
      const int ch = t>>1, c0 = (t&1)*32;
      float sacc = 0.f;
      #pragma unroll
      for (int j=0;j<32;j++) sacc += bf2f(ek[ch*72 + c0 + j]);
      s1a += sacc;
    }
  }
  float* cp = ctxP + (((long)b*64 + chunk)*4 + w)*1024;
  #pragma unroll
  for (int re=0;re<2;re++)
    #pragma unroll
    for (int cd=0;cd<2;cd++)
      #pragma unroll
      for (int ri=0;ri<4;ri++){
        const int e = re*16 + lg*4 + ri, d = cd*16 + lr;
        cp[e*32 + d] = ctx[re][cd][ri];
      }
  const float o = __shfl_xor(s1a, 1, 64);
  if ((t&1)==0) s1P[((long)b*64 + chunk)*128 + (t>>1)] = s1a + o;
}

// ============ K2: reduce partials, build W2 = SCALE*w_out*ctx^T/S1 ============
// grid (4 heads, 8 b), 256 thr.
__global__ __launch_bounds__(256) void k2_w2(const float* __restrict__ ctxP,
    const float* __restrict__ s1P, const float* __restrict__ wout, u16* __restrict__ W2)
{
  const int b = blockIdx.y, h = blockIdx.x, t = threadIdx.x;
  __shared__ float cs[1024];   // ctx^T[e][d]
  __shared__ float s1s[32];
  const float* base = ctxP + ((long)b*256 + h)*1024 + t*4;
  float a0=0.f,a1=0.f,a2=0.f,a3=0.f;
  for (int ch=0; ch<64; ch++){
    f32x4 p4 = *(const f32x4*)(base + (long)ch*4096);
    a0 += p4[0]; a1 += p4[1]; a2 += p4[2]; a3 += p4[3];
  }
  cs[t*4+0]=a0; cs[t*4+1]=a1; cs[t*4+2]=a2; cs[t*4+3]=a3;
  if (t < 32){
    float s = 0.f;
    for (int ch=0; ch<64; ch++) s += s1P[((long)b*64+ch)*128 + h*32 + t];
    s1s[t] = s;
  }
  __syncthreads();
  const int d = t & 31;
  const float rinv = SCALE_F / s1s[d];
  #pragma unroll
  for (int oi=0; oi<8; oi++){
    const int o = (t>>5)*8 + oi;
    float acc = 0.f;
    #pragma unroll
    for (int e=0;e<32;e++) acc += wout[o*128 + h*32 + e] * cs[e*32 + d];
    W2[((long)b*64 + o)*128 + h*32 + d] = f2bf(acc * rinv);
  }
}

// ============ K3: q-proj + softmax_D + y = W2@qsm + b_out -> d_out, stats ============
// grid (512 tiles of 64 tokens, 8 b), 256 thr.
__global__ __launch_bounds__(256) void k3_y(const float* __restrict__ x,
    const float* __restrict__ wqkv, const u16* __restrict__ W2,
    const float* __restrict__ bout, float* __restrict__ y, float* __restrict__ ysum)
{
  const int b = blockIdx.y, blk = blockIdx.x;
  const int t = threadIdx.x, w = t>>6, l = t&63, lr = l&15, lg = l>>4;
  const int n0 = blk*64;
  __shared__ u16 xT[64*72];     // [n][c]
  __shared__ u16 qs[64*136];    // [n][ch] softmaxed q bf16
  __shared__ float red[8];
  const float* xb = x + (long)b*64*NTOK;

  bf16x8 qfr[2][2];   // q rows w*32 .. w*32+31
  #pragma unroll
  for (int rt=0;rt<2;rt++)
    #pragma unroll
    for (int ks=0;ks<2;ks++){
      const float* src = wqkv + (w*32 + rt*16 + lr)*64 + ks*32 + lg*8;
      #pragma unroll
      for (int j=0;j<8;j++) ((u16*)&qfr[rt][ks])[j] = f2bf(src[j]);
    }

  {
    const int c = t>>2, j0 = (t&3)*16;
    #pragma unroll
    for (int i=0;i<4;i++){
      f32x4 v4 = *(const f32x4*)(xb + (long)c*NTOK + n0 + j0 + i*4);
      #pragma unroll
      for (int j=0;j<4;j++) xT[(j0+i*4+j)*72 + c] = f2bf(v4[j]);
    }
  }
  __syncthreads();
  f32x4 qa[2][4];
  #pragma unroll
  for (int rt=0;rt<2;rt++)
    #pragma unroll
    for (int ct=0;ct<4;ct++) qa[rt][ct] = f32x4{0.f,0.f,0.f,0.f};
  #pragma unroll
  for (int ks=0;ks<2;ks++){
    bf16x8 bfr[4];
    #pragma unroll
    for (int ct=0;ct<4;ct++)
      bfr[ct] = *(const bf16x8*)&xT[(ct*16+lr)*72 + ks*32 + lg*8];
    #pragma unroll
    for (int rt=0;rt<2;rt++){
      #pragma unroll
      for (int ct=0;ct<4;ct++)
        qa[rt][ct] = __builtin_amdgcn_mfma_f32_16x16x32_bf16(qfr[rt][ks], bfr[ct], qa[rt][ct], 0,0,0);
    }
  }
  // softmax over the 32 head-dim rows per token column (in-lane + shfl over lg)
  #pragma unroll
  for (int ct=0;ct<4;ct++){
    float e[2][4]; float p = 0.f;
    #pragma unroll
    for (int rt=0;rt<2;rt++)
      #pragma unroll
      for (int ri=0;ri<4;ri++){ e[rt][ri] = __expf(qa[rt][ct][ri]); p += e[rt][ri]; }
    p += __shfl_xor(p, 16, 64);
    p += __shfl_xor(p, 32, 64);
    const float rinv = 1.f/p;
    const int nn = ct*16 + lr;
    #pragma unroll
    for (int rt=0;rt<2;rt++)
      #pragma unroll
      for (int ri=0;ri<4;ri++)
        qs[nn*136 + w*32 + rt*16 + lg*4 + ri] = f2bf(e[rt][ri]*rinv);
  }
  __syncthreads();
  f32x4 ya[4];
  #pragma unroll
  for (int rt=0;rt<4;rt++) ya[rt] = f32x4{0.f,0.f,0.f,0.f};
  #pragma unroll
  for (int ks=0;ks<4;ks++){
    bf16x8 bq = *(const bf16x8*)&qs[(w*16+lr)*136 + ks*32 + lg*8];
    #pragma unroll
    for (int rt=0;rt<4;rt++){
      bf16x8 a = *(const bf16x8*)(W2 + (long)b*8192 + (rt*16+lr)*128 + ks*32 + lg*8);
      ya[rt] = __builtin_amdgcn_mfma_f32_16x16x32_bf16(a, bq, ya[rt], 0,0,0);
    }
  }
  float sum=0.f, ss=0.f;
  float* yb = y + (long)b*64*NTOK;
  #pragma unroll
  for (int rt=0;rt<4;rt++)
    #pragma unroll
    for (int ri=0;ri<4;ri++){
      const int o = rt*16 + lg*4 + ri;
      const int nn = n0 + w*16 + lr;
      const float val = ya[rt][ri] + bout[o];
      sum += val; ss += val*val;
      yb[(long)o*NTOK + nn] = val;
    }
  #pragma unroll
  for (int off=1; off<64; off<<=1){
    sum += __shfl_xor(sum, off, 64);
    ss  += __shfl_xor(ss,  off, 64);
  }
  if (l==0){ red[w*2] = sum; red[w*2+1] = ss; }
  __syncthreads();
  if (t==0){
    ysum[((long)b*512 + blk)*2]   = red[0]+red[2]+red[4]+red[6];
    ysum[((long)b*512 + blk)*2+1] = red[1]+red[3]+red[5]+red[7];
  }
}

// ============ K3b: per-batch mean / rsqrt(var+eps) ============
__global__ __launch_bounds__(256) void k3b_stats(const float* __restrict__ ysum,
                                                 float* __restrict__ musig)
{
  const int b = blockIdx.x, t = threadIdx.x, w = t>>6, l = t&63;
  float s=0.f, q=0.f;
  for (int i=t; i<512; i+=256){
    s += ysum[((long)b*512+i)*2];
    q += ysum[((long)b*512+i)*2+1];
  }
  #pragma unroll
  for (int off=1; off<64; off<<=1){ s += __shfl_xor(s,off,64); q += __shfl_xor(q,off,64); }
  __shared__ float rs[4], rq[4];
  if (l==0){ rs[w]=s; rq[w]=q; }
  __syncthreads();
  if (t==0){
    const float S = rs[0]+rs[1]+rs[2]+rs[3];
    const float Q = rq[0]+rq[1]+rq[2]+rq[3];
    const float inv_n = 1.f/2097152.f;
    const float mu = S*inv_n;
    const float var = Q*inv_n - mu*mu;
    musig[b*2]   = mu;
    musig[b*2+1] = rsqrtf(var + 1e-5f);
  }
}

// ============ K4: normalize + affine, in place on d_out (f32) ============
__global__ __launch_bounds__(256) void k4_norm(float* __restrict__ y,
    const float* __restrict__ musig, const float* __restrict__ gamma,
    const float* __restrict__ beta)
{
  const long idx = ((long)blockIdx.x*256 + threadIdx.x)*4;
  const int b = (int)(idx >> 21);
  const int c = (int)((idx >> 15) & 63);
  const float mu = musig[b*2], inv = musig[b*2+1];
  const float g = gamma[c]*inv, be = beta[c];
  f32x4 v4 = *(const f32x4*)(y + idx);
  #pragma unroll
  for (int j=0;j<4;j++) v4[j] = (v4[j] - mu)*g + be;
  *(f32x4*)(y + idx) = v4;
}

extern "C" void kernel_launch(void* const* d_in, const int* in_sizes, int n_in,
                              void* d_out, int out_size, void* d_ws, size_t ws_size,
                              hipStream_t stream) {
  const float* x     = (const float*)d_in[0];
  const float* wqkv  = (const float*)d_in[1];
  const float* wout  = (const float*)d_in[2];
  const float* bout  = (const float*)d_in[3];
  const float* gamma = (const float*)d_in[4];
  const float* beta  = (const float*)d_in[5];
  float* out = (float*)d_out;
  char* ws = (char*)d_ws;
  if (ws_size < 8814656u) return;  // ~8.9 MB scratch
  float* ctxP = (float*)(ws + 0);         // [8][64][4][32][32] f32 = 8 MB
  float* s1P  = (float*)(ws + 8388608);   // [8][64][128] f32
  u16*  W2    = (u16*) (ws + 8650752);    // [8][64][128] bf16
  float* ysum = (float*)(ws + 8781824);   // [8][512][2] f32
  float* musig= (float*)(ws + 8814592);   // [8][2] f32

  k1_ctx   <<<dim3(64,8), 256, 0, stream>>>(x, wqkv, ctxP, s1P);
  k2_w2    <<<dim3(4,8),  256, 0, stream>>>(ctxP, s1P, wout, W2);
  k3_y     <<<dim3(512,8),256, 0, stream>>>(x, wqkv, W2, bout, out, ysum);
  k3b_stats<<<8,          256, 0, stream>>>(ysum, musig);
  k4_norm  <<<16384,      256, 0, stream>>>(out, musig, gamma, beta);
}